// Round 1
// baseline (823.627 us; speedup 1.0000x reference)
//
#include <hip/hip_runtime.h>
#include <hip/hip_bf16.h>

#define N_NODES 50000
#define N_EDGES 800000
#define DIM 128
#define NREL 8
#define KTOT 1152              // (NREL+1)*DIM
#define NRSEG (N_NODES * NREL) // 400000
#define BN_EPS 1e-5f

typedef __attribute__((ext_vector_type(8))) short bf16x8;
typedef __attribute__((ext_vector_type(4))) float f32x4;

// ---------------- CSR build ----------------

__global__ void k_hist(const int* __restrict__ ei, const int* __restrict__ et,
                       int* __restrict__ cnt) {
    int e = blockIdx.x * 256 + threadIdx.x;
    if (e < N_EDGES) {
        int tgt = ei[N_EDGES + e];
        int r = et[e];
        atomicAdd(&cnt[tgt * NREL + r], 1);
    }
}

// Wave-level exclusive scan + one global atomic per wave to allocate segment
// offsets. Segment order in `sorted` is arbitrary -- only contiguity matters.
__global__ void k_alloc(const int* __restrict__ cnt, int* __restrict__ offs,
                        int* __restrict__ cursor) {
    int i = blockIdx.x * 256 + threadIdx.x;
    int lane = threadIdx.x & 63;
    int c = (i < NRSEG) ? cnt[i] : 0;
    int incl = c;
    #pragma unroll
    for (int d = 1; d < 64; d <<= 1) {
        int t = __shfl_up(incl, d, 64);
        if (lane >= d) incl += t;
    }
    int total = __shfl(incl, 63, 64);
    int base = 0;
    if (lane == 63) base = atomicAdd(cursor, total);
    base = __shfl(base, 63, 64);
    if (i < NRSEG) offs[i] = base + incl - c;
}

__global__ void k_fill(const int* __restrict__ ei, const int* __restrict__ et,
                       const int* __restrict__ offs, int* __restrict__ fillcur,
                       int* __restrict__ sorted) {
    int e = blockIdx.x * 256 + threadIdx.x;
    if (e < N_EDGES) {
        int src = ei[e];
        int tgt = ei[N_EDGES + e];
        int comp = tgt * NREL + et[e];
        int pos = atomicAdd(&fillcur[comp], 1);
        sorted[offs[comp] + pos] = src;
    }
}

// ---------------- weight conversion: Bt[o][r*128+i] = W[r][i][o]; Bt[o][1024+i] = root[i][o]
__global__ void k_wconv(const float* __restrict__ W, const float* __restrict__ root,
                        __hip_bfloat16* __restrict__ Bt) {
    int idx = blockIdx.x * 256 + threadIdx.x;
    if (idx >= DIM * KTOT) return;
    int o = idx / KTOT, k = idx % KTOT;
    float v;
    if (k < NREL * DIM) {
        int r = k >> 7, i = k & 127;
        v = W[(r * DIM + i) * DIM + o];
    } else {
        int i = k - NREL * DIM;
        v = root[i * DIM + o];
    }
    Bt[idx] = __float2bfloat16(v);
}

// ---------------- build A = [mean_r=0..7 | self] in bf16, BN+ReLU applied on the fly
__global__ void k_buildA(const float* __restrict__ xin, const int* __restrict__ cnt,
                         const int* __restrict__ offs, const int* __restrict__ sorted,
                         const float* __restrict__ bnA, const float* __restrict__ bnB,
                         __hip_bfloat16* __restrict__ A) {
    int w = blockIdx.x * 4 + (threadIdx.x >> 6);   // wave-task id, 0..N*9-1
    int lane = threadIdx.x & 63;
    if (w >= N_NODES * 9) return;
    int v = w / 9, rr = w % 9;
    int ch = lane * 2;
    bool bn = (bnA != nullptr);
    float a0 = 1.f, a1 = 1.f, b0 = 0.f, b1 = 0.f;
    if (bn) {
        float2 t = *(const float2*)&bnA[ch]; a0 = t.x; a1 = t.y;
        float2 u = *(const float2*)&bnB[ch]; b0 = u.x; b1 = u.y;
    }
    float s0 = 0.f, s1 = 0.f;
    if (rr < NREL) {
        int comp = v * NREL + rr;
        int c = cnt[comp];
        int o = offs[comp];
        for (int i = 0; i < c; ++i) {
            int s = sorted[o + i];
            float2 xv = *(const float2*)&xin[(size_t)s * DIM + ch];
            float p0 = xv.x, p1 = xv.y;
            if (bn) { p0 = fmaxf(a0 * p0 + b0, 0.f); p1 = fmaxf(a1 * p1 + b1, 0.f); }
            s0 += p0; s1 += p1;
        }
        float inv = (c > 0) ? 1.f / (float)c : 0.f;
        s0 *= inv; s1 *= inv;
        __hip_bfloat162 hv; hv.x = __float2bfloat16(s0); hv.y = __float2bfloat16(s1);
        *(__hip_bfloat162*)&A[(size_t)v * KTOT + rr * DIM + ch] = hv;
    } else {
        float2 xv = *(const float2*)&xin[(size_t)v * DIM + ch];
        float p0 = xv.x, p1 = xv.y;
        if (bn) { p0 = fmaxf(a0 * p0 + b0, 0.f); p1 = fmaxf(a1 * p1 + b1, 0.f); }
        __hip_bfloat162 hv; hv.x = __float2bfloat16(p0); hv.y = __float2bfloat16(p1);
        *(__hip_bfloat162*)&A[(size_t)v * KTOT + NREL * DIM + ch] = hv;
    }
}

// ---------------- GEMM: C[50000,128] = A[50000,1152](bf16) @ Bt^T(bf16) + bias, fp32 out
__global__ __launch_bounds__(256) void k_gemm(const __hip_bfloat16* __restrict__ A,
                                              const __hip_bfloat16* __restrict__ Bt,
                                              const float* __restrict__ bias,
                                              float* __restrict__ C) {
    // LDS stride 56 elems = 112 B: 16B-aligned rows, bank rotation 28 -> 2-way (free)
    __shared__ __hip_bfloat16 As[128][56];
    __shared__ __hip_bfloat16 Bs[128][56];
    int tid = threadIdx.x;
    int m0 = blockIdx.x * 128;
    int lane = tid & 63, wid = tid >> 6;
    int wrow = wid >> 1, wcol = wid & 1;
    f32x4 acc[4][4] = {};
    for (int kt = 0; kt < KTOT / 32; ++kt) {
        int k0 = kt * 32;
        uint4 ra[2], rb[2];
        #pragma unroll
        for (int j = 0; j < 2; ++j) {
            int c = tid + j * 256;          // 512 chunks of 8 bf16
            int row = c >> 2, seg = c & 3;
            int grow = m0 + row;
            if (grow >= N_NODES) grow = N_NODES - 1;  // clamp, stores are guarded
            ra[j] = *(const uint4*)&A[(size_t)grow * KTOT + k0 + seg * 8];
            rb[j] = *(const uint4*)&Bt[(size_t)row * KTOT + k0 + seg * 8];
        }
        __syncthreads();
        #pragma unroll
        for (int j = 0; j < 2; ++j) {
            int c = tid + j * 256;
            int row = c >> 2, seg = c & 3;
            *(uint4*)&As[row][seg * 8] = ra[j];
            *(uint4*)&Bs[row][seg * 8] = rb[j];
        }
        __syncthreads();
        bf16x8 af[4], bfr[4];
        #pragma unroll
        for (int m = 0; m < 4; ++m)
            af[m] = *(const bf16x8*)&As[wrow * 64 + m * 16 + (lane & 15)][(lane >> 4) * 8];
        #pragma unroll
        for (int n = 0; n < 4; ++n)
            bfr[n] = *(const bf16x8*)&Bs[wcol * 64 + n * 16 + (lane & 15)][(lane >> 4) * 8];
        #pragma unroll
        for (int m = 0; m < 4; ++m)
            #pragma unroll
            for (int n = 0; n < 4; ++n)
                acc[m][n] = __builtin_amdgcn_mfma_f32_16x16x32_bf16(af[m], bfr[n], acc[m][n], 0, 0, 0);
    }
    #pragma unroll
    for (int m = 0; m < 4; ++m) {
        int row = m0 + wrow * 64 + m * 16 + (lane >> 4) * 4;
        #pragma unroll
        for (int n = 0; n < 4; ++n) {
            int col = wcol * 64 + n * 16 + (lane & 15);
            float bv = bias[col];
            #pragma unroll
            for (int j = 0; j < 4; ++j) {
                int r = row + j;
                if (r < N_NODES) C[(size_t)r * DIM + col] = acc[m][n][j] + bv;
            }
        }
    }
}

// ---------------- BN stats: per-channel sum and sumsq
__global__ void k_bnstats(const float* __restrict__ h, float* __restrict__ stats) {
    int c = threadIdx.x & 127;
    int half = threadIdx.x >> 7;
    float s = 0.f, q = 0.f;
    for (int v = blockIdx.x * 2 + half; v < N_NODES; v += gridDim.x * 2) {
        float x = h[(size_t)v * DIM + c];
        s += x; q += x * x;
    }
    __shared__ float ls[256], lq[256];
    ls[threadIdx.x] = s; lq[threadIdx.x] = q;
    __syncthreads();
    if (half == 0) {
        s += ls[c + 128]; q += lq[c + 128];
        atomicAdd(&stats[c], s);
        atomicAdd(&stats[128 + c], q);
    }
}

__global__ void k_bnfinal(const float* __restrict__ stats, const float* __restrict__ g,
                          const float* __restrict__ be, float* __restrict__ bn) {
    int c = threadIdx.x;
    float mean = stats[c] / (float)N_NODES;
    float var = stats[128 + c] / (float)N_NODES - mean * mean;
    float a = g[c] * rsqrtf(var + BN_EPS);
    bn[c] = a;
    bn[128 + c] = be[c] - mean * a;
}

// ---------------- classifier: out[v,0:2] = relu(bn(h2[v])) @ cw + cb
__global__ void k_classifier(const float* __restrict__ h, const float* __restrict__ bn,
                             const float* __restrict__ cw, const float* __restrict__ cb,
                             float* __restrict__ out) {
    int w = blockIdx.x * 4 + (threadIdx.x >> 6);
    int lane = threadIdx.x & 63;
    if (w >= N_NODES) return;
    float acc0 = 0.f, acc1 = 0.f;
    #pragma unroll
    for (int half = 0; half < 2; ++half) {
        int c = lane + half * 64;
        float x = h[(size_t)w * DIM + c];
        float p = fmaxf(bn[c] * x + bn[128 + c], 0.f);
        acc0 += p * cw[c * 2];
        acc1 += p * cw[c * 2 + 1];
    }
    #pragma unroll
    for (int d = 32; d; d >>= 1) {
        acc0 += __shfl_down(acc0, d, 64);
        acc1 += __shfl_down(acc1, d, 64);
    }
    if (lane == 0) {
        out[w * 2] = acc0 + cb[0];
        out[w * 2 + 1] = acc1 + cb[1];
    }
}

extern "C" void kernel_launch(void* const* d_in, const int* in_sizes, int n_in,
                              void* d_out, int out_size, void* d_ws, size_t ws_size,
                              hipStream_t stream) {
    const float* x    = (const float*)d_in[0];
    const int*   ei   = (const int*)d_in[1];
    const int*   et   = (const int*)d_in[2];
    const float* w1   = (const float*)d_in[3];
    const float* root1= (const float*)d_in[4];
    const float* b1   = (const float*)d_in[5];
    const float* g1   = (const float*)d_in[6];
    const float* be1  = (const float*)d_in[7];
    const float* w2   = (const float*)d_in[8];
    const float* root2= (const float*)d_in[9];
    const float* b2   = (const float*)d_in[10];
    const float* g2   = (const float*)d_in[11];
    const float* be2  = (const float*)d_in[12];
    const float* cw   = (const float*)d_in[13];
    const float* cb   = (const float*)d_in[14];
    float* out = (float*)d_out;

    char* ws = (char*)d_ws;
    size_t off = 0;
    auto alloc = [&](size_t bytes) -> char* {
        char* p = ws + off;
        off += (bytes + 255) & ~(size_t)255;
        return p;
    };
    int*   cnt     = (int*)alloc((size_t)NRSEG * 4);
    int*   offs    = (int*)alloc((size_t)NRSEG * 4);
    int*   fillcur = (int*)alloc((size_t)NRSEG * 4);
    int*   cursor  = (int*)alloc(256);
    float* stats1  = (float*)alloc(1024);
    float* stats2  = (float*)alloc(1024);
    size_t zero_bytes = off;                    // everything above must start at 0
    float* bn1     = (float*)alloc(1024);
    float* bn2     = (float*)alloc(1024);
    __hip_bfloat16* Bt1 = (__hip_bfloat16*)alloc((size_t)DIM * KTOT * 2);
    __hip_bfloat16* Bt2 = (__hip_bfloat16*)alloc((size_t)DIM * KTOT * 2);
    int*   sorted  = (int*)alloc((size_t)N_EDGES * 4);
    float* h1      = (float*)alloc((size_t)N_NODES * DIM * 4);
    float* h2      = (float*)alloc((size_t)N_NODES * DIM * 4);
    __hip_bfloat16* A = (__hip_bfloat16*)alloc((size_t)N_NODES * KTOT * 2);

    hipMemsetAsync(d_ws, 0, zero_bytes, stream);

    k_hist<<<(N_EDGES + 255) / 256, 256, 0, stream>>>(ei, et, cnt);
    k_alloc<<<(NRSEG + 255) / 256, 256, 0, stream>>>(cnt, offs, cursor);
    k_fill<<<(N_EDGES + 255) / 256, 256, 0, stream>>>(ei, et, offs, fillcur, sorted);
    k_wconv<<<(DIM * KTOT + 255) / 256, 256, 0, stream>>>(w1, root1, Bt1);
    k_wconv<<<(DIM * KTOT + 255) / 256, 256, 0, stream>>>(w2, root2, Bt2);

    // layer 1
    k_buildA<<<(N_NODES * 9) / 4, 256, 0, stream>>>(x, cnt, offs, sorted, nullptr, nullptr, A);
    k_gemm<<<(N_NODES + 127) / 128, 256, 0, stream>>>(A, Bt1, b1, h1);
    k_bnstats<<<256, 256, 0, stream>>>(h1, stats1);
    k_bnfinal<<<1, 128, 0, stream>>>(stats1, g1, be1, bn1);

    // layer 2
    k_buildA<<<(N_NODES * 9) / 4, 256, 0, stream>>>(h1, cnt, offs, sorted, bn1, bn1 + 128, A);
    k_gemm<<<(N_NODES + 127) / 128, 256, 0, stream>>>(A, Bt2, b2, h2);
    k_bnstats<<<256, 256, 0, stream>>>(h2, stats2);
    k_bnfinal<<<1, 128, 0, stream>>>(stats2, g2, be2, bn2);

    k_classifier<<<(N_NODES + 3) / 4, 256, 0, stream>>>(h2, bn2, cw, cb, out);
}

// Round 2
// 691.158 us; speedup vs baseline: 1.1917x; 1.1917x over previous
//
#include <hip/hip_runtime.h>
#include <hip/hip_bf16.h>

#define N_NODES 50000
#define N_EDGES 800000
#define DIM 128
#define NREL 8
#define KTOT 1152              // (NREL+1)*DIM
#define NRSEG (N_NODES * NREL) // 400000
#define BN_EPS 1e-5f

typedef __attribute__((ext_vector_type(8))) short bf16x8;
typedef __attribute__((ext_vector_type(4))) float f32x4;

__device__ inline float b2f(short s) {
    union { unsigned u; float f; } t;
    t.u = ((unsigned)(unsigned short)s) << 16;
    return t.f;
}
__device__ inline short f2b(float f) {
    __hip_bfloat16 h = __float2bfloat16(f);
    return *reinterpret_cast<short*>(&h);
}

// ---------------- CSR build ----------------

__global__ void k_hist(const int* __restrict__ ei, const int* __restrict__ et,
                       int* __restrict__ cnt) {
    int e = blockIdx.x * 256 + threadIdx.x;
    if (e < N_EDGES) {
        int tgt = ei[N_EDGES + e];
        int r = et[e];
        atomicAdd(&cnt[tgt * NREL + r], 1);
    }
}

__global__ void k_alloc(const int* __restrict__ cnt, int* __restrict__ offs,
                        int* __restrict__ cursor) {
    int i = blockIdx.x * 256 + threadIdx.x;
    int lane = threadIdx.x & 63;
    int c = (i < NRSEG) ? cnt[i] : 0;
    int incl = c;
    #pragma unroll
    for (int d = 1; d < 64; d <<= 1) {
        int t = __shfl_up(incl, d, 64);
        if (lane >= d) incl += t;
    }
    int total = __shfl(incl, 63, 64);
    int base = 0;
    if (lane == 63) base = atomicAdd(cursor, total);
    base = __shfl(base, 63, 64);
    if (i < NRSEG) offs[i] = base + incl - c;
}

__global__ void k_fill(const int* __restrict__ ei, const int* __restrict__ et,
                       const int* __restrict__ offs, int* __restrict__ fillcur,
                       int* __restrict__ sorted) {
    int e = blockIdx.x * 256 + threadIdx.x;
    if (e < N_EDGES) {
        int src = ei[e];
        int tgt = ei[N_EDGES + e];
        int comp = tgt * NREL + et[e];
        int pos = atomicAdd(&fillcur[comp], 1);
        sorted[offs[comp] + pos] = src;
    }
}

// ---------------- weight conversion: Bt[o][r*128+i] = W[r][i][o]; Bt[o][1024+i] = root[i][o]
__global__ void k_wconv(const float* __restrict__ W, const float* __restrict__ root,
                        __hip_bfloat16* __restrict__ Bt) {
    int idx = blockIdx.x * 256 + threadIdx.x;
    if (idx >= DIM * KTOT) return;
    int o = idx / KTOT, k = idx % KTOT;
    float v;
    if (k < NREL * DIM) {
        int r = k >> 7, i = k & 127;
        v = W[(r * DIM + i) * DIM + o];
    } else {
        int i = k - NREL * DIM;
        v = root[i * DIM + o];
    }
    Bt[idx] = __float2bfloat16(v);
}

// ---------------- cast input to bf16, optionally fused BN(scale,shift)+ReLU
__global__ void k_cast(const float* __restrict__ in, const float* __restrict__ bn,
                       __hip_bfloat16* __restrict__ out) {
    int i = (blockIdx.x * 256 + threadIdx.x) * 4;
    if (i >= N_NODES * DIM) return;
    float4 v = *(const float4*)&in[i];
    if (bn) {
        int ch = i & 127;
        float4 a = *(const float4*)&bn[ch];
        float4 b = *(const float4*)&bn[128 + ch];
        v.x = fmaxf(v.x * a.x + b.x, 0.f);
        v.y = fmaxf(v.y * a.y + b.y, 0.f);
        v.z = fmaxf(v.z * a.z + b.z, 0.f);
        v.w = fmaxf(v.w * a.w + b.w, 0.f);
    }
    short4 o;
    o.x = f2b(v.x); o.y = f2b(v.y); o.z = f2b(v.z); o.w = f2b(v.w);
    *(short4*)&out[i] = o;
}

// ---------------- build A = [mean_r=0..7 | self] bf16; one wave per node.
// Lane layout: group g = lane>>4 handles edge i%4==g; il = lane&15 handles
// channels il*8..il*8+7 (bf16x8 = 16B load -> 16 lanes cover the 256B row).
__global__ void k_buildA2(const __hip_bfloat16* __restrict__ xb,
                          const int* __restrict__ cnt, const int* __restrict__ offs,
                          const int* __restrict__ sorted,
                          __hip_bfloat16* __restrict__ A) {
    int w = blockIdx.x * 4 + (threadIdx.x >> 6);   // node id
    if (w >= N_NODES) return;
    int lane = threadIdx.x & 63;
    int g = lane >> 4, il = lane & 15;
    int c8 = 0, o8 = 0;
    if (lane < 8) { c8 = cnt[w * NREL + lane]; o8 = offs[w * NREL + lane]; }
    // self row (read now, write at end)
    bf16x8 selfv = *(const bf16x8*)&xb[(size_t)w * DIM + il * 8];
    #pragma unroll 1
    for (int r = 0; r < NREL; ++r) {
        int c = __shfl(c8, r, 64);
        int o = __shfl(o8, r, 64);
        float s[8] = {0.f, 0.f, 0.f, 0.f, 0.f, 0.f, 0.f, 0.f};
        for (int i = g; i < c; i += 4) {
            int idx = sorted[o + i];
            bf16x8 rv = *(const bf16x8*)&xb[(size_t)idx * DIM + il * 8];
            #pragma unroll
            for (int j = 0; j < 8; ++j) s[j] += b2f(rv[j]);
        }
        #pragma unroll
        for (int j = 0; j < 8; ++j) {
            s[j] += __shfl_xor(s[j], 16, 64);
            s[j] += __shfl_xor(s[j], 32, 64);
        }
        if (g == 0) {
            float inv = (c > 0) ? 1.f / (float)c : 0.f;
            bf16x8 ov;
            #pragma unroll
            for (int j = 0; j < 8; ++j) ov[j] = f2b(s[j] * inv);
            *(bf16x8*)&A[(size_t)w * KTOT + r * DIM + il * 8] = ov;
        }
    }
    if (g == 0)
        *(bf16x8*)&A[(size_t)w * KTOT + NREL * DIM + il * 8] = selfv;
}

// ---------------- GEMM: C[50000,128] = A[50000,1152](bf16) @ Bt^T(bf16) + bias, fp32 out
__global__ __launch_bounds__(256) void k_gemm(const __hip_bfloat16* __restrict__ A,
                                              const __hip_bfloat16* __restrict__ Bt,
                                              const float* __restrict__ bias,
                                              float* __restrict__ C) {
    __shared__ __hip_bfloat16 As[128][56];
    __shared__ __hip_bfloat16 Bs[128][56];
    int tid = threadIdx.x;
    int m0 = blockIdx.x * 128;
    int lane = tid & 63, wid = tid >> 6;
    int wrow = wid >> 1, wcol = wid & 1;
    f32x4 acc[4][4] = {};
    for (int kt = 0; kt < KTOT / 32; ++kt) {
        int k0 = kt * 32;
        uint4 ra[2], rb[2];
        #pragma unroll
        for (int j = 0; j < 2; ++j) {
            int c = tid + j * 256;          // 512 chunks of 8 bf16
            int row = c >> 2, seg = c & 3;
            int grow = m0 + row;
            if (grow >= N_NODES) grow = N_NODES - 1;
            ra[j] = *(const uint4*)&A[(size_t)grow * KTOT + k0 + seg * 8];
            rb[j] = *(const uint4*)&Bt[(size_t)row * KTOT + k0 + seg * 8];
        }
        __syncthreads();
        #pragma unroll
        for (int j = 0; j < 2; ++j) {
            int c = tid + j * 256;
            int row = c >> 2, seg = c & 3;
            *(uint4*)&As[row][seg * 8] = ra[j];
            *(uint4*)&Bs[row][seg * 8] = rb[j];
        }
        __syncthreads();
        bf16x8 af[4], bfr[4];
        #pragma unroll
        for (int m = 0; m < 4; ++m)
            af[m] = *(const bf16x8*)&As[wrow * 64 + m * 16 + (lane & 15)][(lane >> 4) * 8];
        #pragma unroll
        for (int n = 0; n < 4; ++n)
            bfr[n] = *(const bf16x8*)&Bs[wcol * 64 + n * 16 + (lane & 15)][(lane >> 4) * 8];
        #pragma unroll
        for (int m = 0; m < 4; ++m)
            #pragma unroll
            for (int n = 0; n < 4; ++n)
                acc[m][n] = __builtin_amdgcn_mfma_f32_16x16x32_bf16(af[m], bfr[n], acc[m][n], 0, 0, 0);
    }
    #pragma unroll
    for (int m = 0; m < 4; ++m) {
        int row = m0 + wrow * 64 + m * 16 + (lane >> 4) * 4;
        #pragma unroll
        for (int n = 0; n < 4; ++n) {
            int col = wcol * 64 + n * 16 + (lane & 15);
            float bv = bias[col];
            #pragma unroll
            for (int j = 0; j < 4; ++j) {
                int r = row + j;
                if (r < N_NODES) C[(size_t)r * DIM + col] = acc[m][n][j] + bv;
            }
        }
    }
}

// ---------------- BN stats: per-channel sum and sumsq
__global__ void k_bnstats(const float* __restrict__ h, float* __restrict__ stats) {
    int c = threadIdx.x & 127;
    int half = threadIdx.x >> 7;
    float s = 0.f, q = 0.f;
    for (int v = blockIdx.x * 2 + half; v < N_NODES; v += gridDim.x * 2) {
        float x = h[(size_t)v * DIM + c];
        s += x; q += x * x;
    }
    __shared__ float ls[256], lq[256];
    ls[threadIdx.x] = s; lq[threadIdx.x] = q;
    __syncthreads();
    if (half == 0) {
        s += ls[c + 128]; q += lq[c + 128];
        atomicAdd(&stats[c], s);
        atomicAdd(&stats[128 + c], q);
    }
}

__global__ void k_bnfinal(const float* __restrict__ stats, const float* __restrict__ g,
                          const float* __restrict__ be, float* __restrict__ bn) {
    int c = threadIdx.x;
    float mean = stats[c] / (float)N_NODES;
    float var = stats[128 + c] / (float)N_NODES - mean * mean;
    float a = g[c] * rsqrtf(var + BN_EPS);
    bn[c] = a;
    bn[128 + c] = be[c] - mean * a;
}

// ---------------- classifier: out[v,0:2] = relu(bn(h2[v])) @ cw + cb
__global__ void k_classifier(const float* __restrict__ h, const float* __restrict__ bn,
                             const float* __restrict__ cw, const float* __restrict__ cb,
                             float* __restrict__ out) {
    int w = blockIdx.x * 4 + (threadIdx.x >> 6);
    int lane = threadIdx.x & 63;
    if (w >= N_NODES) return;
    float acc0 = 0.f, acc1 = 0.f;
    #pragma unroll
    for (int half = 0; half < 2; ++half) {
        int c = lane + half * 64;
        float x = h[(size_t)w * DIM + c];
        float p = fmaxf(bn[c] * x + bn[128 + c], 0.f);
        acc0 += p * cw[c * 2];
        acc1 += p * cw[c * 2 + 1];
    }
    #pragma unroll
    for (int d = 32; d; d >>= 1) {
        acc0 += __shfl_down(acc0, d, 64);
        acc1 += __shfl_down(acc1, d, 64);
    }
    if (lane == 0) {
        out[w * 2] = acc0 + cb[0];
        out[w * 2 + 1] = acc1 + cb[1];
    }
}

extern "C" void kernel_launch(void* const* d_in, const int* in_sizes, int n_in,
                              void* d_out, int out_size, void* d_ws, size_t ws_size,
                              hipStream_t stream) {
    const float* x    = (const float*)d_in[0];
    const int*   ei   = (const int*)d_in[1];
    const int*   et   = (const int*)d_in[2];
    const float* w1   = (const float*)d_in[3];
    const float* root1= (const float*)d_in[4];
    const float* b1   = (const float*)d_in[5];
    const float* g1   = (const float*)d_in[6];
    const float* be1  = (const float*)d_in[7];
    const float* w2   = (const float*)d_in[8];
    const float* root2= (const float*)d_in[9];
    const float* b2   = (const float*)d_in[10];
    const float* g2   = (const float*)d_in[11];
    const float* be2  = (const float*)d_in[12];
    const float* cw   = (const float*)d_in[13];
    const float* cb   = (const float*)d_in[14];
    float* out = (float*)d_out;

    char* ws = (char*)d_ws;
    size_t off = 0;
    auto alloc = [&](size_t bytes) -> char* {
        char* p = ws + off;
        off += (bytes + 255) & ~(size_t)255;
        return p;
    };
    int*   cnt     = (int*)alloc((size_t)NRSEG * 4);
    int*   offs    = (int*)alloc((size_t)NRSEG * 4);
    int*   fillcur = (int*)alloc((size_t)NRSEG * 4);
    int*   cursor  = (int*)alloc(256);
    float* stats1  = (float*)alloc(1024);
    float* stats2  = (float*)alloc(1024);
    size_t zero_bytes = off;                    // everything above must start at 0
    float* bn1     = (float*)alloc(1024);
    float* bn2     = (float*)alloc(1024);
    __hip_bfloat16* Bt1 = (__hip_bfloat16*)alloc((size_t)DIM * KTOT * 2);
    __hip_bfloat16* Bt2 = (__hip_bfloat16*)alloc((size_t)DIM * KTOT * 2);
    int*   sorted  = (int*)alloc((size_t)N_EDGES * 4);
    float* h1      = (float*)alloc((size_t)N_NODES * DIM * 4);
    float* h2      = (float*)alloc((size_t)N_NODES * DIM * 4);
    __hip_bfloat16* xb = (__hip_bfloat16*)alloc((size_t)N_NODES * DIM * 2);
    __hip_bfloat16* A  = (__hip_bfloat16*)alloc((size_t)N_NODES * KTOT * 2);

    hipMemsetAsync(d_ws, 0, zero_bytes, stream);

    k_hist<<<(N_EDGES + 255) / 256, 256, 0, stream>>>(ei, et, cnt);
    k_alloc<<<(NRSEG + 255) / 256, 256, 0, stream>>>(cnt, offs, cursor);
    k_fill<<<(N_EDGES + 255) / 256, 256, 0, stream>>>(ei, et, offs, fillcur, sorted);
    k_wconv<<<(DIM * KTOT + 255) / 256, 256, 0, stream>>>(w1, root1, Bt1);
    k_wconv<<<(DIM * KTOT + 255) / 256, 256, 0, stream>>>(w2, root2, Bt2);

    int cast_grid = (N_NODES * DIM / 4 + 255) / 256;

    // layer 1
    k_cast<<<cast_grid, 256, 0, stream>>>(x, nullptr, xb);
    k_buildA2<<<(N_NODES + 3) / 4, 256, 0, stream>>>(xb, cnt, offs, sorted, A);
    k_gemm<<<(N_NODES + 127) / 128, 256, 0, stream>>>(A, Bt1, b1, h1);
    k_bnstats<<<256, 256, 0, stream>>>(h1, stats1);
    k_bnfinal<<<1, 128, 0, stream>>>(stats1, g1, be1, bn1);

    // layer 2
    k_cast<<<cast_grid, 256, 0, stream>>>(h1, bn1, xb);
    k_buildA2<<<(N_NODES + 3) / 4, 256, 0, stream>>>(xb, cnt, offs, sorted, A);
    k_gemm<<<(N_NODES + 127) / 128, 256, 0, stream>>>(A, Bt2, b2, h2);
    k_bnstats<<<256, 256, 0, stream>>>(h2, stats2);
    k_bnfinal<<<1, 128, 0, stream>>>(stats2, g2, be2, bn2);

    k_classifier<<<(N_NODES + 3) / 4, 256, 0, stream>>>(h2, bn2, cw, cb, out);
}

// Round 3
// 657.312 us; speedup vs baseline: 1.2530x; 1.0515x over previous
//
#include <hip/hip_runtime.h>
#include <hip/hip_bf16.h>

#define N_NODES 50000
#define N_EDGES 800000
#define DIM 128
#define NREL 8
#define KTOT 1152              // (NREL+1)*DIM
#define NRSEG (N_NODES * NREL) // 400000
#define BN_EPS 1e-5f

typedef __attribute__((ext_vector_type(8))) short bf16x8;
typedef __attribute__((ext_vector_type(4))) float f32x4;
typedef __attribute__((ext_vector_type(16))) float f32x16;

__device__ inline float b2f(short s) {
    union { unsigned u; float f; } t;
    t.u = ((unsigned)(unsigned short)s) << 16;
    return t.f;
}
__device__ inline short f2b(float f) {
    __hip_bfloat16 h = __float2bfloat16(f);
    return *reinterpret_cast<short*>(&h);
}

// ---------------- CSR build ----------------

__global__ void k_hist(const int* __restrict__ ei, const int* __restrict__ et,
                       int* __restrict__ cnt) {
    int e = blockIdx.x * 256 + threadIdx.x;
    if (e < N_EDGES) {
        int tgt = ei[N_EDGES + e];
        int r = et[e];
        atomicAdd(&cnt[tgt * NREL + r], 1);
    }
}

__global__ void k_alloc(const int* __restrict__ cnt, int* __restrict__ offs,
                        int* __restrict__ cursor) {
    int i = blockIdx.x * 256 + threadIdx.x;
    int lane = threadIdx.x & 63;
    int c = (i < NRSEG) ? cnt[i] : 0;
    int incl = c;
    #pragma unroll
    for (int d = 1; d < 64; d <<= 1) {
        int t = __shfl_up(incl, d, 64);
        if (lane >= d) incl += t;
    }
    int total = __shfl(incl, 63, 64);
    int base = 0;
    if (lane == 63) base = atomicAdd(cursor, total);
    base = __shfl(base, 63, 64);
    if (i < NRSEG) offs[i] = base + incl - c;
}

__global__ void k_fill(const int* __restrict__ ei, const int* __restrict__ et,
                       const int* __restrict__ offs, int* __restrict__ fillcur,
                       int* __restrict__ sorted) {
    int e = blockIdx.x * 256 + threadIdx.x;
    if (e < N_EDGES) {
        int src = ei[e];
        int tgt = ei[N_EDGES + e];
        int comp = tgt * NREL + et[e];
        int pos = atomicAdd(&fillcur[comp], 1);
        sorted[offs[comp] + pos] = src;
    }
}

// ---------------- weight conversion: Bt[o][r*128+i] = W[r][i][o]; Bt[o][1024+i] = root[i][o]
__global__ void k_wconv(const float* __restrict__ W, const float* __restrict__ root,
                        __hip_bfloat16* __restrict__ Bt) {
    int idx = blockIdx.x * 256 + threadIdx.x;
    if (idx >= DIM * KTOT) return;
    int o = idx / KTOT, k = idx % KTOT;
    float v;
    if (k < NREL * DIM) {
        int r = k >> 7, i = k & 127;
        v = W[(r * DIM + i) * DIM + o];
    } else {
        int i = k - NREL * DIM;
        v = root[i * DIM + o];
    }
    Bt[idx] = __float2bfloat16(v);
}

// ---------------- cast input to bf16, optionally fused BN(scale,shift)+ReLU
__global__ void k_cast(const float* __restrict__ in, const float* __restrict__ bn,
                       __hip_bfloat16* __restrict__ out) {
    int i = (blockIdx.x * 256 + threadIdx.x) * 4;
    if (i >= N_NODES * DIM) return;
    float4 v = *(const float4*)&in[i];
    if (bn) {
        int ch = i & 127;
        float4 a = *(const float4*)&bn[ch];
        float4 b = *(const float4*)&bn[128 + ch];
        v.x = fmaxf(v.x * a.x + b.x, 0.f);
        v.y = fmaxf(v.y * a.y + b.y, 0.f);
        v.z = fmaxf(v.z * a.z + b.z, 0.f);
        v.w = fmaxf(v.w * a.w + b.w, 0.f);
    }
    short4 o;
    o.x = f2b(v.x); o.y = f2b(v.y); o.z = f2b(v.z); o.w = f2b(v.w);
    *(short4*)&out[i] = o;
}

// ---------------- build A = [mean_r=0..7 | self] bf16; one wave per node.
__global__ void k_buildA2(const __hip_bfloat16* __restrict__ xb,
                          const int* __restrict__ cnt, const int* __restrict__ offs,
                          const int* __restrict__ sorted,
                          __hip_bfloat16* __restrict__ A) {
    int w = blockIdx.x * 4 + (threadIdx.x >> 6);   // node id
    if (w >= N_NODES) return;
    int lane = threadIdx.x & 63;
    int g = lane >> 4, il = lane & 15;
    int c8 = 0, o8 = 0;
    if (lane < 8) { c8 = cnt[w * NREL + lane]; o8 = offs[w * NREL + lane]; }
    bf16x8 selfv = *(const bf16x8*)&xb[(size_t)w * DIM + il * 8];
    #pragma unroll 1
    for (int r = 0; r < NREL; ++r) {
        int c = __shfl(c8, r, 64);
        int o = __shfl(o8, r, 64);
        float s[8] = {0.f, 0.f, 0.f, 0.f, 0.f, 0.f, 0.f, 0.f};
        for (int i = g; i < c; i += 4) {
            int idx = sorted[o + i];
            bf16x8 rv = *(const bf16x8*)&xb[(size_t)idx * DIM + il * 8];
            #pragma unroll
            for (int j = 0; j < 8; ++j) s[j] += b2f(rv[j]);
        }
        #pragma unroll
        for (int j = 0; j < 8; ++j) {
            s[j] += __shfl_xor(s[j], 16, 64);
            s[j] += __shfl_xor(s[j], 32, 64);
        }
        if (g == 0) {
            float inv = (c > 0) ? 1.f / (float)c : 0.f;
            bf16x8 ov;
            #pragma unroll
            for (int j = 0; j < 8; ++j) ov[j] = f2b(s[j] * inv);
            *(bf16x8*)&A[(size_t)w * KTOT + r * DIM + il * 8] = ov;
        }
    }
    if (g == 0)
        *(bf16x8*)&A[(size_t)w * KTOT + NREL * DIM + il * 8] = selfv;
}

// ---------------- GEMM v2: barrier-free, one wave per 32-row tile.
// C[50000,128] = A[50000,1152](bf16) @ Bt[128,1152]^T (bf16) + bias, fp32 out.
// mfma_f32_32x32x16_bf16: A-frag lane l: row=l&31, k=(l>>5)*8+j (bf16x8).
// B-frag lane l: col=l&31, k=(l>>5)*8+j -> with Bt row-major [col][k], the
// load pattern is identical to A. C/D: col=lane&31, row=(reg&3)+8*(reg>>2)+4*(lane>>5).
#define LOADC(kstep, aBuf, bBuf)                                              \
    {                                                                         \
        _Pragma("unroll")                                                     \
        for (int s = 0; s < 2; ++s) {                                         \
            int koff = ((kstep) + s) * 16;                                    \
            aBuf[s] = *(const bf16x8*)(aBase + koff);                         \
            _Pragma("unroll")                                                 \
            for (int n = 0; n < 4; ++n)                                       \
                bBuf[s][n] = *(const bf16x8*)(bBase + (size_t)n * 32 * KTOT + koff); \
        }                                                                     \
    }

#define MFMA8(aBuf, bBuf)                                                     \
    {                                                                         \
        _Pragma("unroll")                                                     \
        for (int s = 0; s < 2; ++s) {                                         \
            _Pragma("unroll")                                                 \
            for (int n = 0; n < 4; ++n)                                       \
                acc[n] = __builtin_amdgcn_mfma_f32_32x32x16_bf16(             \
                    aBuf[s], bBuf[s][n], acc[n], 0, 0, 0);                    \
        }                                                                     \
    }

__global__ __launch_bounds__(64) void k_gemm2(const __hip_bfloat16* __restrict__ A,
                                              const __hip_bfloat16* __restrict__ Bt,
                                              const float* __restrict__ bias,
                                              float* __restrict__ C) {
    int lane = threadIdx.x;
    int m0 = blockIdx.x * 32;
    int half = lane >> 5, l31 = lane & 31;
    int arow = m0 + l31;
    if (arow >= N_NODES) arow = N_NODES - 1;   // clamp loads; stores guarded
    const __hip_bfloat16* aBase = A + (size_t)arow * KTOT + half * 8;
    const __hip_bfloat16* bBase = Bt + (size_t)l31 * KTOT + half * 8;

    f32x16 acc[4] = {};
    bf16x8 aA[2], aB[2];
    bf16x8 bA[2][4], bB[2][4];

    LOADC(0, aA, bA);
    // 72 k-steps (K=16 each) = 36 chunks of 2, processed as 18 chunk-pairs
    for (int c = 0; c < 36; c += 2) {
        LOADC((c + 1) * 2, aB, bB);
        MFMA8(aA, bA);
        if (c + 2 < 36) LOADC((c + 2) * 2, aA, bA);
        MFMA8(aB, bB);
    }

    #pragma unroll
    for (int n = 0; n < 4; ++n) {
        int col = n * 32 + l31;
        float bv = bias[col];
        #pragma unroll
        for (int reg = 0; reg < 16; ++reg) {
            int r = m0 + (reg & 3) + 8 * (reg >> 2) + 4 * half;
            if (r < N_NODES) C[(size_t)r * DIM + col] = acc[n][reg] + bv;
        }
    }
}

// ---------------- BN stats: per-channel sum and sumsq
__global__ void k_bnstats(const float* __restrict__ h, float* __restrict__ stats) {
    int c = threadIdx.x & 127;
    int half = threadIdx.x >> 7;
    float s = 0.f, q = 0.f;
    for (int v = blockIdx.x * 2 + half; v < N_NODES; v += gridDim.x * 2) {
        float x = h[(size_t)v * DIM + c];
        s += x; q += x * x;
    }
    __shared__ float ls[256], lq[256];
    ls[threadIdx.x] = s; lq[threadIdx.x] = q;
    __syncthreads();
    if (half == 0) {
        s += ls[c + 128]; q += lq[c + 128];
        atomicAdd(&stats[c], s);
        atomicAdd(&stats[128 + c], q);
    }
}

__global__ void k_bnfinal(const float* __restrict__ stats, const float* __restrict__ g,
                          const float* __restrict__ be, float* __restrict__ bn) {
    int c = threadIdx.x;
    float mean = stats[c] / (float)N_NODES;
    float var = stats[128 + c] / (float)N_NODES - mean * mean;
    float a = g[c] * rsqrtf(var + BN_EPS);
    bn[c] = a;
    bn[128 + c] = be[c] - mean * a;
}

// ---------------- classifier: out[v,0:2] = relu(bn(h2[v])) @ cw + cb
__global__ void k_classifier(const float* __restrict__ h, const float* __restrict__ bn,
                             const float* __restrict__ cw, const float* __restrict__ cb,
                             float* __restrict__ out) {
    int w = blockIdx.x * 4 + (threadIdx.x >> 6);
    int lane = threadIdx.x & 63;
    if (w >= N_NODES) return;
    float acc0 = 0.f, acc1 = 0.f;
    #pragma unroll
    for (int half = 0; half < 2; ++half) {
        int c = lane + half * 64;
        float x = h[(size_t)w * DIM + c];
        float p = fmaxf(bn[c] * x + bn[128 + c], 0.f);
        acc0 += p * cw[c * 2];
        acc1 += p * cw[c * 2 + 1];
    }
    #pragma unroll
    for (int d = 32; d; d >>= 1) {
        acc0 += __shfl_down(acc0, d, 64);
        acc1 += __shfl_down(acc1, d, 64);
    }
    if (lane == 0) {
        out[w * 2] = acc0 + cb[0];
        out[w * 2 + 1] = acc1 + cb[1];
    }
}

extern "C" void kernel_launch(void* const* d_in, const int* in_sizes, int n_in,
                              void* d_out, int out_size, void* d_ws, size_t ws_size,
                              hipStream_t stream) {
    const float* x    = (const float*)d_in[0];
    const int*   ei   = (const int*)d_in[1];
    const int*   et   = (const int*)d_in[2];
    const float* w1   = (const float*)d_in[3];
    const float* root1= (const float*)d_in[4];
    const float* b1   = (const float*)d_in[5];
    const float* g1   = (const float*)d_in[6];
    const float* be1  = (const float*)d_in[7];
    const float* w2   = (const float*)d_in[8];
    const float* root2= (const float*)d_in[9];
    const float* b2   = (const float*)d_in[10];
    const float* g2   = (const float*)d_in[11];
    const float* be2  = (const float*)d_in[12];
    const float* cw   = (const float*)d_in[13];
    const float* cb   = (const float*)d_in[14];
    float* out = (float*)d_out;

    char* ws = (char*)d_ws;
    size_t off = 0;
    auto alloc = [&](size_t bytes) -> char* {
        char* p = ws + off;
        off += (bytes + 255) & ~(size_t)255;
        return p;
    };
    int*   cnt     = (int*)alloc((size_t)NRSEG * 4);
    int*   offs    = (int*)alloc((size_t)NRSEG * 4);
    int*   fillcur = (int*)alloc((size_t)NRSEG * 4);
    int*   cursor  = (int*)alloc(256);
    float* stats1  = (float*)alloc(1024);
    float* stats2  = (float*)alloc(1024);
    size_t zero_bytes = off;                    // everything above must start at 0
    float* bn1     = (float*)alloc(1024);
    float* bn2     = (float*)alloc(1024);
    __hip_bfloat16* Bt1 = (__hip_bfloat16*)alloc((size_t)DIM * KTOT * 2);
    __hip_bfloat16* Bt2 = (__hip_bfloat16*)alloc((size_t)DIM * KTOT * 2);
    int*   sorted  = (int*)alloc((size_t)N_EDGES * 4);
    float* h1      = (float*)alloc((size_t)N_NODES * DIM * 4);
    float* h2      = (float*)alloc((size_t)N_NODES * DIM * 4);
    __hip_bfloat16* xb = (__hip_bfloat16*)alloc((size_t)N_NODES * DIM * 2);
    __hip_bfloat16* A  = (__hip_bfloat16*)alloc((size_t)N_NODES * KTOT * 2);

    hipMemsetAsync(d_ws, 0, zero_bytes, stream);

    k_hist<<<(N_EDGES + 255) / 256, 256, 0, stream>>>(ei, et, cnt);
    k_alloc<<<(NRSEG + 255) / 256, 256, 0, stream>>>(cnt, offs, cursor);
    k_fill<<<(N_EDGES + 255) / 256, 256, 0, stream>>>(ei, et, offs, fillcur, sorted);
    k_wconv<<<(DIM * KTOT + 255) / 256, 256, 0, stream>>>(w1, root1, Bt1);
    k_wconv<<<(DIM * KTOT + 255) / 256, 256, 0, stream>>>(w2, root2, Bt2);

    int cast_grid = (N_NODES * DIM / 4 + 255) / 256;
    int gemm_grid = (N_NODES + 31) / 32;   // 1563 one-wave blocks

    // layer 1
    k_cast<<<cast_grid, 256, 0, stream>>>(x, nullptr, xb);
    k_buildA2<<<(N_NODES + 3) / 4, 256, 0, stream>>>(xb, cnt, offs, sorted, A);
    k_gemm2<<<gemm_grid, 64, 0, stream>>>(A, Bt1, b1, h1);
    k_bnstats<<<256, 256, 0, stream>>>(h1, stats1);
    k_bnfinal<<<1, 128, 0, stream>>>(stats1, g1, be1, bn1);

    // layer 2
    k_cast<<<cast_grid, 256, 0, stream>>>(h1, bn1, xb);
    k_buildA2<<<(N_NODES + 3) / 4, 256, 0, stream>>>(xb, cnt, offs, sorted, A);
    k_gemm2<<<gemm_grid, 64, 0, stream>>>(A, Bt2, b2, h2);
    k_bnstats<<<256, 256, 0, stream>>>(h2, stats2);
    k_bnfinal<<<1, 128, 0, stream>>>(stats2, g2, be2, bn2);

    k_classifier<<<(N_NODES + 3) / 4, 256, 0, stream>>>(h2, bn2, cw, cb, out);
}

// Round 4
// 604.725 us; speedup vs baseline: 1.3620x; 1.0870x over previous
//
#include <hip/hip_runtime.h>
#include <hip/hip_bf16.h>

#define N_NODES 50000
#define N_EDGES 800000
#define DIM 128
#define NREL 8
#define KTOT 1152              // (NREL+1)*DIM
#define NRSEG (N_NODES * NREL) // 400000
#define BN_EPS 1e-5f

typedef __attribute__((ext_vector_type(8))) short bf16x8;
typedef __attribute__((ext_vector_type(16))) float f32x16;

__device__ inline float b2f(short s) {
    union { unsigned u; float f; } t;
    t.u = ((unsigned)(unsigned short)s) << 16;
    return t.f;
}
__device__ inline short f2b(float f) {
    __hip_bfloat16 h = __float2bfloat16(f);
    return *reinterpret_cast<short*>(&h);
}

// ---------------- CSR build ----------------

__global__ void k_hist(const int* __restrict__ ei, const int* __restrict__ et,
                       int* __restrict__ cnt) {
    int e = blockIdx.x * 256 + threadIdx.x;
    if (e < N_EDGES) {
        int tgt = ei[N_EDGES + e];
        int r = et[e];
        atomicAdd(&cnt[tgt * NREL + r], 1);
    }
}

__global__ void k_alloc(const int* __restrict__ cnt, int* __restrict__ offs,
                        int* __restrict__ cursor) {
    int i = blockIdx.x * 256 + threadIdx.x;
    int lane = threadIdx.x & 63;
    int c = (i < NRSEG) ? cnt[i] : 0;
    int incl = c;
    #pragma unroll
    for (int d = 1; d < 64; d <<= 1) {
        int t = __shfl_up(incl, d, 64);
        if (lane >= d) incl += t;
    }
    int total = __shfl(incl, 63, 64);
    int base = 0;
    if (lane == 63) base = atomicAdd(cursor, total);
    base = __shfl(base, 63, 64);
    if (i < NRSEG) offs[i] = base + incl - c;
}

__global__ void k_fill(const int* __restrict__ ei, const int* __restrict__ et,
                       const int* __restrict__ offs, int* __restrict__ fillcur,
                       int* __restrict__ sorted) {
    int e = blockIdx.x * 256 + threadIdx.x;
    if (e < N_EDGES) {
        int src = ei[e];
        int tgt = ei[N_EDGES + e];
        int comp = tgt * NREL + et[e];
        int pos = atomicAdd(&fillcur[comp], 1);
        sorted[offs[comp] + pos] = src;
    }
}

// ---------------- weight conversion: Bt[o][r*128+i] = W[r][i][o]; Bt[o][1024+i] = root[i][o]
__global__ void k_wconv(const float* __restrict__ W, const float* __restrict__ root,
                        __hip_bfloat16* __restrict__ Bt) {
    int idx = blockIdx.x * 256 + threadIdx.x;
    if (idx >= DIM * KTOT) return;
    int o = idx / KTOT, k = idx % KTOT;
    float v;
    if (k < NREL * DIM) {
        int r = k >> 7, i = k & 127;
        v = W[(r * DIM + i) * DIM + o];
    } else {
        int i = k - NREL * DIM;
        v = root[i * DIM + o];
    }
    Bt[idx] = __float2bfloat16(v);
}

// ---------------- cast fp32 input -> bf16
__global__ void k_cast(const float* __restrict__ in, __hip_bfloat16* __restrict__ out) {
    int i = (blockIdx.x * 256 + threadIdx.x) * 4;
    if (i >= N_NODES * DIM) return;
    float4 v = *(const float4*)&in[i];
    short4 o;
    o.x = f2b(v.x); o.y = f2b(v.y); o.z = f2b(v.z); o.w = f2b(v.w);
    *(short4*)&out[i] = o;
}

// ---------------- cast bf16 h + BN(scale,shift)+ReLU -> bf16
__global__ void k_cast2(const __hip_bfloat16* __restrict__ in, const float* __restrict__ bn,
                        __hip_bfloat16* __restrict__ out) {
    int i = (blockIdx.x * 256 + threadIdx.x) * 8;
    if (i >= N_NODES * DIM) return;
    bf16x8 v = *(const bf16x8*)&in[i];
    int ch = i & 127;
    bf16x8 o;
    #pragma unroll
    for (int j = 0; j < 8; ++j) {
        float f = b2f(v[j]);
        f = fmaxf(f * bn[ch + j] + bn[128 + ch + j], 0.f);
        o[j] = f2b(f);
    }
    *(bf16x8*)&out[i] = o;
}

// ---------------- fused RGCN layer:
// per block: 64 nodes. Loop over 9 K-slices (8 relation means + self):
//   stage At[64][128] bf16 in LDS (swizzled), then MFMA against Bt slice.
// Epilogue: +bias, write h (bf16), atomic BN stats (sum, sumsq).
// MFMA 32x32x16: A-frag lane l: row=l&31, k=(l>>5)*8+j; B-frag lane l:
// col=l&31, k=(l>>5)*8+j; C/D: col=lane&31, row=(reg&3)+8*(reg>>2)+4*(lane>>5).
__global__ __launch_bounds__(256) void k_fused(
        const __hip_bfloat16* __restrict__ xb,
        const int* __restrict__ cnt, const int* __restrict__ offs,
        const int* __restrict__ sorted,
        const __hip_bfloat16* __restrict__ Bt,
        const float* __restrict__ bias,
        __hip_bfloat16* __restrict__ h, float* __restrict__ stats) {
    __shared__ __hip_bfloat16 At[64 * 128];   // rows of 256B, 16B-slot swizzle
    int tid = threadIdx.x;
    int n0 = blockIdx.x * 64;
    int g = tid >> 4, il = tid & 15;          // gather role: 16 groups x 16 lanes
    int lane = tid & 63, wid = tid >> 6;      // mfma role
    int half = lane >> 5, l31 = lane & 31;
    int rbase = (wid & 1) * 32, cbase = (wid >> 1) * 64;

    const __hip_bfloat16* bBase0 = Bt + (size_t)(cbase + l31) * KTOT + half * 8;
    const __hip_bfloat16* bBase1 = Bt + (size_t)(cbase + 32 + l31) * KTOT + half * 8;

    f32x16 acc0 = {}, acc1 = {};

    for (int r = 0; r < 9; ++r) {
        // ---- stage phase: group g stages rows vi = g, g+16, g+32, g+48
        if (r < 8) {
            int c4[4], o4[4];
            float s4[4][8];
            #pragma unroll
            for (int s = 0; s < 4; ++s) {
                int node = n0 + g + s * 16;
                bool ok = node < N_NODES;
                int comp = node * NREL + r;
                c4[s] = ok ? cnt[comp] : 0;
                o4[s] = ok ? offs[comp] : 0;
                #pragma unroll
                for (int j = 0; j < 8; ++j) s4[s][j] = 0.f;
            }
            int mx = max(max(c4[0], c4[1]), max(c4[2], c4[3]));
            for (int i = 0; i < mx; ++i) {
                #pragma unroll
                for (int s = 0; s < 4; ++s) {
                    if (i < c4[s]) {
                        int idx = sorted[o4[s] + i];
                        bf16x8 rv = *(const bf16x8*)&xb[(size_t)idx * DIM + il * 8];
                        #pragma unroll
                        for (int j = 0; j < 8; ++j) s4[s][j] += b2f(rv[j]);
                    }
                }
            }
            #pragma unroll
            for (int s = 0; s < 4; ++s) {
                int vi = g + s * 16;
                float inv = (c4[s] > 0) ? 1.f / (float)c4[s] : 0.f;
                bf16x8 ov;
                #pragma unroll
                for (int j = 0; j < 8; ++j) ov[j] = f2b(s4[s][j] * inv);
                int slot = il ^ (vi & 15);
                *(bf16x8*)&At[vi * 128 + slot * 8] = ov;
            }
        } else {
            #pragma unroll
            for (int s = 0; s < 4; ++s) {
                int vi = g + s * 16;
                int node = n0 + vi;
                bf16x8 rv = {};
                if (node < N_NODES) rv = *(const bf16x8*)&xb[(size_t)node * DIM + il * 8];
                int slot = il ^ (vi & 15);
                *(bf16x8*)&At[vi * 128 + slot * 8] = rv;
            }
        }
        __syncthreads();
        // ---- mfma phase: K=128 slice r
        const __hip_bfloat16* b0 = bBase0 + r * DIM;
        const __hip_bfloat16* b1 = bBase1 + r * DIM;
        int arow = rbase + l31;
        #pragma unroll
        for (int ks = 0; ks < 8; ++ks) {
            int slot = (2 * ks + half) ^ (arow & 15);
            bf16x8 a = *(const bf16x8*)&At[arow * 128 + slot * 8];
            bf16x8 f0 = *(const bf16x8*)(b0 + ks * 16);
            bf16x8 f1 = *(const bf16x8*)(b1 + ks * 16);
            acc0 = __builtin_amdgcn_mfma_f32_32x32x16_bf16(a, f0, acc0, 0, 0, 0);
            acc1 = __builtin_amdgcn_mfma_f32_32x32x16_bf16(a, f1, acc1, 0, 0, 0);
        }
        __syncthreads();
    }

    // ---- epilogue: bias, store h (bf16), BN stats
    float bv0 = bias[cbase + l31];
    float bv1 = bias[cbase + 32 + l31];
    float s1a = 0.f, s2a = 0.f, s1b = 0.f, s2b = 0.f;
    #pragma unroll
    for (int reg = 0; reg < 16; ++reg) {
        int row = n0 + rbase + (reg & 3) + 8 * (reg >> 2) + 4 * half;
        float v0 = acc0[reg] + bv0;
        float v1 = acc1[reg] + bv1;
        if (row < N_NODES) {
            h[(size_t)row * DIM + cbase + l31] = __float2bfloat16(v0);
            h[(size_t)row * DIM + cbase + 32 + l31] = __float2bfloat16(v1);
            s1a += v0; s2a += v0 * v0;
            s1b += v1; s2b += v1 * v1;
        }
    }
    s1a += __shfl_xor(s1a, 32, 64); s2a += __shfl_xor(s2a, 32, 64);
    s1b += __shfl_xor(s1b, 32, 64); s2b += __shfl_xor(s2b, 32, 64);
    if (half == 0) {
        atomicAdd(&stats[cbase + l31], s1a);
        atomicAdd(&stats[128 + cbase + l31], s2a);
        atomicAdd(&stats[cbase + 32 + l31], s1b);
        atomicAdd(&stats[128 + cbase + 32 + l31], s2b);
    }
}

__global__ void k_bnfinal(const float* __restrict__ stats, const float* __restrict__ g,
                          const float* __restrict__ be, float* __restrict__ bn) {
    int c = threadIdx.x;
    float mean = stats[c] / (float)N_NODES;
    float var = stats[128 + c] / (float)N_NODES - mean * mean;
    float a = g[c] * rsqrtf(var + BN_EPS);
    bn[c] = a;
    bn[128 + c] = be[c] - mean * a;
}

// ---------------- classifier: out[v,0:2] = relu(bn(h2[v])) @ cw + cb
__global__ void k_classifier(const __hip_bfloat16* __restrict__ h, const float* __restrict__ bn,
                             const float* __restrict__ cw, const float* __restrict__ cb,
                             float* __restrict__ out) {
    int w = blockIdx.x * 4 + (threadIdx.x >> 6);
    int lane = threadIdx.x & 63;
    if (w >= N_NODES) return;
    int c = lane * 2;
    __hip_bfloat162 hv = *(const __hip_bfloat162*)&h[(size_t)w * DIM + c];
    float x0 = __bfloat162float(hv.x), x1 = __bfloat162float(hv.y);
    float p0 = fmaxf(x0 * bn[c] + bn[128 + c], 0.f);
    float p1 = fmaxf(x1 * bn[c + 1] + bn[128 + c + 1], 0.f);
    float acc0 = p0 * cw[c * 2] + p1 * cw[(c + 1) * 2];
    float acc1 = p0 * cw[c * 2 + 1] + p1 * cw[(c + 1) * 2 + 1];
    #pragma unroll
    for (int d = 32; d; d >>= 1) {
        acc0 += __shfl_down(acc0, d, 64);
        acc1 += __shfl_down(acc1, d, 64);
    }
    if (lane == 0) {
        out[w * 2] = acc0 + cb[0];
        out[w * 2 + 1] = acc1 + cb[1];
    }
}

extern "C" void kernel_launch(void* const* d_in, const int* in_sizes, int n_in,
                              void* d_out, int out_size, void* d_ws, size_t ws_size,
                              hipStream_t stream) {
    const float* x    = (const float*)d_in[0];
    const int*   ei   = (const int*)d_in[1];
    const int*   et   = (const int*)d_in[2];
    const float* w1   = (const float*)d_in[3];
    const float* root1= (const float*)d_in[4];
    const float* b1   = (const float*)d_in[5];
    const float* g1   = (const float*)d_in[6];
    const float* be1  = (const float*)d_in[7];
    const float* w2   = (const float*)d_in[8];
    const float* root2= (const float*)d_in[9];
    const float* b2   = (const float*)d_in[10];
    const float* g2   = (const float*)d_in[11];
    const float* be2  = (const float*)d_in[12];
    const float* cw   = (const float*)d_in[13];
    const float* cb   = (const float*)d_in[14];
    float* out = (float*)d_out;

    char* ws = (char*)d_ws;
    size_t off = 0;
    auto alloc = [&](size_t bytes) -> char* {
        char* p = ws + off;
        off += (bytes + 255) & ~(size_t)255;
        return p;
    };
    // zeroed region first
    int*   cnt     = (int*)alloc((size_t)NRSEG * 4);
    int*   fillcur = (int*)alloc((size_t)NRSEG * 4);
    int*   cursor  = (int*)alloc(256);
    float* stats1  = (float*)alloc(1024);
    float* stats2  = (float*)alloc(1024);
    size_t zero_bytes = off;
    int*   offs    = (int*)alloc((size_t)NRSEG * 4);
    float* bn1     = (float*)alloc(1024);
    float* bn2     = (float*)alloc(1024);
    __hip_bfloat16* Bt1 = (__hip_bfloat16*)alloc((size_t)DIM * KTOT * 2);
    __hip_bfloat16* Bt2 = (__hip_bfloat16*)alloc((size_t)DIM * KTOT * 2);
    int*   sorted  = (int*)alloc((size_t)N_EDGES * 4);
    __hip_bfloat16* h1 = (__hip_bfloat16*)alloc((size_t)N_NODES * DIM * 2);
    __hip_bfloat16* h2 = (__hip_bfloat16*)alloc((size_t)N_NODES * DIM * 2);
    __hip_bfloat16* xb = (__hip_bfloat16*)alloc((size_t)N_NODES * DIM * 2);

    hipMemsetAsync(d_ws, 0, zero_bytes, stream);

    k_hist<<<(N_EDGES + 255) / 256, 256, 0, stream>>>(ei, et, cnt);
    k_alloc<<<(NRSEG + 255) / 256, 256, 0, stream>>>(cnt, offs, cursor);
    k_fill<<<(N_EDGES + 255) / 256, 256, 0, stream>>>(ei, et, offs, fillcur, sorted);
    k_wconv<<<(DIM * KTOT + 255) / 256, 256, 0, stream>>>(w1, root1, Bt1);
    k_wconv<<<(DIM * KTOT + 255) / 256, 256, 0, stream>>>(w2, root2, Bt2);

    int fused_grid = (N_NODES + 63) / 64;   // 782

    // layer 1
    k_cast<<<(N_NODES * DIM / 4 + 255) / 256, 256, 0, stream>>>(x, xb);
    k_fused<<<fused_grid, 256, 0, stream>>>(xb, cnt, offs, sorted, Bt1, b1, h1, stats1);
    k_bnfinal<<<1, 128, 0, stream>>>(stats1, g1, be1, bn1);

    // layer 2
    k_cast2<<<(N_NODES * DIM / 8 + 255) / 256, 256, 0, stream>>>(h1, bn1, xb);
    k_fused<<<fused_grid, 256, 0, stream>>>(xb, cnt, offs, sorted, Bt2, b2, h2, stats2);
    k_bnfinal<<<1, 128, 0, stream>>>(stats2, g2, be2, bn2);

    k_classifier<<<(N_NODES + 3) / 4, 256, 0, stream>>>(h2, bn2, cw, cb, out);
}